// Round 8
// baseline (296.364 us; speedup 1.0000x reference)
//
#include <hip/hip_runtime.h>

// PPO loss, T = 2^23 fp32 — ROUND 8: INSTRUMENTATION ROUND.
// Main kernel = round-7 (passing, absmax 0.0, ~45us) verbatim.
// Added two probe kernels (no stores; kept live via asm) to ablate the ~3 TB/s wall:
//   probe_math  : 256x per-element loss arithmetic, zero memory  -> VALU/transcendental cost
//   probe_stream: 3 passes over all 4 arrays (402 MB), dense f4  -> deliverable memory BW
// Probes run AFTER main so main's cache environment matches rounds 1-7 exactly.

#define T_TOTAL 8388608L
#define WCHUNK  2048
#define TILE    512
#define NWAVES  4096
#define NBLK    1024
#define NT      256

#define EPSF 0.2f
#define GF   0.99f
#define C1F  0.5f
#define C2F  0.01f
#define AGLF ((float)(0.99 * 0.95))

constexpr float fpowc(double a, int n) {
    double r = 1.0;
    for (int i = 0; i < n; ++i) r *= a;
    return (r < 1e-40) ? 0.0f : (float)r;
}
constexpr float AG4   = fpowc(0.99 * 0.95, 4);
constexpr float AG8   = fpowc(0.99 * 0.95, 8);
constexpr float AG16  = fpowc(0.99 * 0.95, 16);
constexpr float AG32  = fpowc(0.99 * 0.95, 32);
constexpr float AG64  = fpowc(0.99 * 0.95, 64);
constexpr float AG128 = fpowc(0.99 * 0.95, 128);
constexpr float AG256 = fpowc(0.99 * 0.95, 256);
constexpr float G8    = fpowc(0.99, 8);
constexpr float G16   = fpowc(0.99, 16);
constexpr float G32   = fpowc(0.99, 32);
constexpr float G64   = fpowc(0.99, 64);
constexpr float G128  = fpowc(0.99, 128);
constexpr float G256  = fpowc(0.99, 256);
constexpr float G12   = fpowc(0.99, 12);
constexpr float G24   = fpowc(0.99, 24);
constexpr float G48   = fpowc(0.99, 48);
constexpr float G96   = fpowc(0.99, 96);
constexpr float G192  = fpowc(0.99, 192);
constexpr float G384  = fpowc(0.99, 384);

__device__ __forceinline__ float4 ld4(const float* p) {
    return *reinterpret_cast<const float4*>(p);
}

__device__ __forceinline__ float wscan(float val, float w, int lane) {
#pragma unroll
    for (int s = 1; s < 64; s <<= 1) {
        float o = __shfl_down(val, s, 64);
        val += (lane + s < 64) ? w * o : 0.0f;
        w *= w;
    }
    return val;
}

struct TileRegs { float4 r0, r1, v0, v1, p0, p1, q0, q1; };

__device__ __forceinline__ void load_tile(TileRegs& X,
    const float* __restrict__ P, const float* __restrict__ Q,
    const float* __restrict__ R, const float* __restrict__ V,
    long tb, int lane)
{
    const long a = tb + 8L * lane;
    X.r0 = ld4(R + a); X.r1 = ld4(R + a + 4);
    X.v0 = ld4(V + a); X.v1 = ld4(V + a + 4);
    X.p0 = ld4(P + a); X.p1 = ld4(P + a + 4);
    X.q0 = ld4(Q + a); X.q1 = ld4(Q + a + 4);
}

__device__ __forceinline__ void proc_tile(const TileRegs& X, float vedge,
    float wgl, float wrl, int lane, float& Cg, float& Cr, float& acc)
{
    float t0 = __shfl_down(X.v0.x, 1, 64);
    const float vn7 = (lane < 63) ? t0 : vedge;
    const float rr[8] = {X.r0.x,X.r0.y,X.r0.z,X.r0.w,X.r1.x,X.r1.y,X.r1.z,X.r1.w};
    const float vv[8] = {X.v0.x,X.v0.y,X.v0.z,X.v0.w,X.v1.x,X.v1.y,X.v1.z,X.v1.w};
    const float vx[8] = {X.v0.y,X.v0.z,X.v0.w,X.v1.x,X.v1.y,X.v1.z,X.v1.w,vn7};
    float d[8];
#pragma unroll
    for (int i = 0; i < 8; ++i) d[i] = rr[i] - vv[i] + GF * vx[i];

    float Pg = 0.0f, Pr = 0.0f;
#pragma unroll
    for (int i = 7; i >= 0; --i) {
        Pg = fmaf(AGLF, Pg, d[i]);
        Pr = fmaf(GF,   Pr, rr[i]);
    }
    const float Ug = wscan(Pg, AG8, lane);
    const float Ur = wscan(Pr, G8,  lane);
    float sng = __shfl_down(Ug, 1, 64); sng = (lane < 63) ? sng : 0.0f;
    float snr = __shfl_down(Ur, 1, 64); snr = (lane < 63) ? snr : 0.0f;

    float y  = fmaf(wgl, Cg, sng);
    float tt = fmaf(wrl, Cr, snr);

    const float pp[8] = {X.p0.x,X.p0.y,X.p0.z,X.p0.w,X.p1.x,X.p1.y,X.p1.z,X.p1.w};
    const float qq[8] = {X.q0.x,X.q0.y,X.q0.z,X.q0.w,X.q1.x,X.q1.y,X.q1.z,X.q1.w};
#pragma unroll
    for (int i = 7; i >= 0; --i) {
        y  = fmaf(AGLF, y, d[i]);
        tt = fmaf(GF, tt, rr[i]);
        const float rt   = __fdividef(pp[i], qq[i]);
        const float cl   = fminf(fmaxf(rt, 1.0f - EPSF), 1.0f + EPSF);
        const float term = fminf(rt * y, cl * y);
        const float vd   = vv[i] - tt;
        acc = fmaf(C1F * vd, vd, acc) - term - C2F * pp[i] * __logf(pp[i] + 1e-5f);
    }
    Cg = __shfl(y,  0, 64);
    Cr = __shfl(tt, 0, 64);
}

__global__ __launch_bounds__(NT) void ppo_main(
    const float* __restrict__ probs,
    const float* __restrict__ probs_old,
    const float* __restrict__ rewards,
    const float* __restrict__ values,
    float* __restrict__ part)
{
    const int  j    = threadIdx.x;
    const int  lane = j & 63;
    const int  wid  = j >> 6;
    const int  gw   = blockIdx.x * 4 + wid;
    const long wb   = (long)gw * WCHUNK;
    const bool has_halo = (gw != NWAVES - 1);

    TileRegs A, B;
    load_tile(A, probs, probs_old, rewards, values, wb + 3L * TILE, lane);
    float4 h0, h1, h2, hgr, hgv;
    float  hve = 0.0f;
    if (has_halo) {
        const long he = wb + WCHUNK;
        h0  = ld4(rewards + he + 12L * lane);
        h1  = ld4(rewards + he + 12L * lane + 4);
        h2  = ld4(rewards + he + 12L * lane + 8);
        hgr = ld4(rewards + he + 4L * lane);
        hgv = ld4(values  + he + 4L * lane);
        hve = values[he + 256];
    } else {
        h0 = h1 = h2 = hgr = hgv = make_float4(0.f, 0.f, 0.f, 0.f);
    }
    load_tile(B, probs, probs_old, rewards, values, wb + 2L * TILE, lane);
    const float vend = has_halo ? values[wb + WCHUNK] : 0.0f;
    const float ve2  = values[wb + 1536];
    const float ve1  = values[wb + 1024];
    const float ve0  = values[wb + 512];

    const int k63 = 63 - lane;
    float wgl = 1.f, wrl = 1.f;
    if (k63 & 1)  { wgl *= AG8;   wrl *= G8;   }
    if (k63 & 2)  { wgl *= AG16;  wrl *= G16;  }
    if (k63 & 4)  { wgl *= AG32;  wrl *= G32;  }
    if (k63 & 8)  { wgl *= AG64;  wrl *= G64;  }
    if (k63 & 16) { wgl *= AG128; wrl *= G128; }
    if (k63 & 32) { wgl *= AG256; wrl *= G256; }
    float pg4 = 1.f, pr12 = 1.f;
    if (lane & 1)  { pg4 *= AG4;   pr12 *= G12;  }
    if (lane & 2)  { pg4 *= AG8;   pr12 *= G24;  }
    if (lane & 4)  { pg4 *= AG16;  pr12 *= G48;  }
    if (lane & 8)  { pg4 *= AG32;  pr12 *= G96;  }
    if (lane & 16) { pg4 *= AG64;  pr12 *= G192; }
    if (lane & 32) { pg4 *= AG128; pr12 *= G384; }

    float Kg = 0.0f, Kr = 0.0f;
    if (has_halo) {
        float t = __shfl_down(hgv.x, 1, 64);
        const float vn3 = (lane < 63) ? t : hve;
        const float d0 = hgr.x - hgv.x + GF * hgv.y;
        const float d1 = hgr.y - hgv.y + GF * hgv.z;
        const float d2 = hgr.z - hgv.z + GF * hgv.w;
        const float d3 = hgr.w - hgv.w + GF * vn3;
        float kg = (d0 + AGLF * (d1 + AGLF * (d2 + AGLF * d3))) * pg4;
        float kr = h2.w;
        kr = fmaf(GF, kr, h2.z); kr = fmaf(GF, kr, h2.y); kr = fmaf(GF, kr, h2.x);
        kr = fmaf(GF, kr, h1.w); kr = fmaf(GF, kr, h1.z); kr = fmaf(GF, kr, h1.y);
        kr = fmaf(GF, kr, h1.x); kr = fmaf(GF, kr, h0.w); kr = fmaf(GF, kr, h0.z);
        kr = fmaf(GF, kr, h0.y); kr = fmaf(GF, kr, h0.x);
        kr *= pr12;
#pragma unroll
        for (int s = 1; s < 64; s <<= 1) {
            kg += __shfl_xor(kg, s, 64);
            kr += __shfl_xor(kr, s, 64);
        }
        Kg = kg; Kr = kr;
    }

    float Cg = Kg, Cr = Kr, acc = 0.0f;
    proc_tile(A, vend, wgl, wrl, lane, Cg, Cr, acc);
    load_tile(A, probs, probs_old, rewards, values, wb + 1L * TILE, lane);
    proc_tile(B, ve2, wgl, wrl, lane, Cg, Cr, acc);
    load_tile(B, probs, probs_old, rewards, values, wb, lane);
    proc_tile(A, ve1, wgl, wrl, lane, Cg, Cr, acc);
    proc_tile(B, ve0, wgl, wrl, lane, Cg, Cr, acc);

#pragma unroll
    for (int s = 32; s >= 1; s >>= 1) acc += __shfl_down(acc, s, 64);
    if (lane == 0) part[gw] = acc;
}

__global__ __launch_bounds__(256) void ppo_reduce(
    const float* __restrict__ part, float* __restrict__ out)
{
    __shared__ float s[4];
    const int j = threadIdx.x, lane = j & 63, wid = j >> 6;
    const float4 a = ld4(part + 16 * j);
    const float4 b = ld4(part + 16 * j + 4);
    const float4 c = ld4(part + 16 * j + 8);
    const float4 d = ld4(part + 16 * j + 12);
    float x = ((a.x + a.y) + (a.z + a.w)) + ((b.x + b.y) + (b.z + b.w))
            + ((c.x + c.y) + (c.z + c.w)) + ((d.x + d.y) + (d.z + d.w));
#pragma unroll
    for (int s2 = 32; s2 >= 1; s2 >>= 1) x += __shfl_down(x, s2, 64);
    if (lane == 0) s[wid] = x;
    __syncthreads();
    if (j == 0) out[0] = (s[0] + s[1]) + (s[2] + s[3]);
}

// ---------------- PROBE 1: pure VALU/transcendental loss-math, zero memory -------------
// 2048 blocks x 256 thr, 256 iterations of the per-element loss body each.
// 256 iters x 524288 thr = 16x the real per-element math volume of one full pass.
__global__ __launch_bounds__(256) void probe_math()
{
    float y  = (float)threadIdx.x * 1e-3f + 0.5f;
    float tt = (float)blockIdx.x  * 1e-4f + 0.3f;
    float p  = 0.5f + (float)(threadIdx.x & 15) * 0.01f;
    float q  = 0.6f + (float)(blockIdx.x & 7)   * 0.01f;
    const float r = 0.1f, v = 0.2f, dd = 0.05f;
    float acc = 0.0f;
#pragma unroll 8
    for (int i = 0; i < 256; ++i) {
        y  = fmaf(AGLF, y, dd);
        tt = fmaf(GF, tt, r);
        const float rt   = __fdividef(p, q);
        const float cl   = fminf(fmaxf(rt, 1.0f - EPSF), 1.0f + EPSF);
        const float term = fminf(rt * y, cl * y);
        const float vd   = v - tt;
        acc = fmaf(C1F * vd, vd, acc) - term - C2F * p * __logf(p + 1e-5f);
        p += 1e-6f; q += 1e-6f;       // keep div/log loop-variant (no hoisting)
    }
    asm volatile("" :: "v"(acc));     // keep everything live, no store
}

// ---------------- PROBE 2: streaming read, 3 full passes over all 4 arrays ------------
// 2048 blocks x 256 thr = 8192 waves (full nominal occupancy), dense float4 per lane.
// 12 iters x 4 arrays x 16B x 524288 thr = 402.7 MB logical.
__global__ __launch_bounds__(256) void probe_stream(
    const float* __restrict__ p0, const float* __restrict__ p1,
    const float* __restrict__ p2, const float* __restrict__ p3)
{
    const long t = (long)blockIdx.x * 256 + threadIdx.x;   // 0..524287
    float acc = 0.0f;
#pragma unroll
    for (int k = 0; k < 12; ++k) {
        const long off = ((long)(k & 3) * 524288L + t) * 4L;
        const float4 a = ld4(p0 + off);
        const float4 b = ld4(p1 + off);
        const float4 c = ld4(p2 + off);
        const float4 d = ld4(p3 + off);
        acc += ((a.x + a.y) + (a.z + a.w)) + ((b.x + b.y) + (b.z + b.w))
             + ((c.x + c.y) + (c.z + c.w)) + ((d.x + d.y) + (d.z + d.w));
    }
    asm volatile("" :: "v"(acc));     // keep loads live, no store
}

extern "C" void kernel_launch(void* const* d_in, const int* in_sizes, int n_in,
                              void* d_out, int out_size, void* d_ws, size_t ws_size,
                              hipStream_t stream) {
    const float* probs     = (const float*)d_in[0];
    const float* probs_old = (const float*)d_in[1];
    const float* rewards   = (const float*)d_in[2];
    const float* values    = (const float*)d_in[3];
    float* part = (float*)d_ws;
    float* out  = (float*)d_out;

    // real computation first (cache environment identical to rounds 1-7)
    ppo_main<<<NBLK, NT, 0, stream>>>(probs, probs_old, rewards, values, part);
    ppo_reduce<<<1, 256, 0, stream>>>(part, out);
    // probes (output-invariant; measured via rocprof dispatch table)
    probe_math<<<2048, 256, 0, stream>>>();
    probe_stream<<<2048, 256, 0, stream>>>(probs, probs_old, rewards, values);
}